// Round 7
// baseline (1449.259 us; speedup 1.0000x reference)
//
#include <hip/hip_runtime.h>

typedef float  f32x4  __attribute__((ext_vector_type(4)));
typedef float  f32x16 __attribute__((ext_vector_type(16)));
typedef short  short8 __attribute__((ext_vector_type(8)));
typedef unsigned int uint4v __attribute__((ext_vector_type(4)));

#define LOG2E 1.4426950408889634f
#define NPIX 4096
#define CCH  512
#define DQK  64

__device__ __forceinline__ ushort f2b(float f) {
  union { float f; unsigned u; } v; v.f = f;
  unsigned r = v.u + 0x7fffu + ((v.u >> 16) & 1u);
  return (ushort)(r >> 16);
}

__device__ __forceinline__ unsigned cvt_pk_bf16(float lo, float hi) {
  unsigned r;
  asm("v_cvt_pk_bf16_f32 %0, %1, %2" : "=v"(r) : "v"(lo), "v"(hi));
  return r;
}

// in-place half-swap: a' = {a[0:32), b[0:32)}, b' = {a[32:64), b[32:64)}
__device__ __forceinline__ void plane_swap(unsigned &a, unsigned &b) {
  asm volatile("v_permlane32_swap_b32 %0, %1" : "+v"(a), "+v"(b));
}

// async 16B global -> LDS (dest = wave-uniform base + lane*16)
__device__ __forceinline__ void gload16(const ushort* g, ushort* l) {
  __builtin_amdgcn_global_load_lds((const __attribute__((address_space(1))) void*)g,
                                   (__attribute__((address_space(3))) void*)l, 16, 0, 0);
}

// x: [B][C][N] f32  ->  Xt: [B][N][C] bf16  (tiled transpose via LDS)
__global__ __launch_bounds__(256) void k_cast_x(const float* __restrict__ x,
                                                ushort* __restrict__ Xt) {
  __shared__ float tile[32][33];
  const int b = blockIdx.z;
  const int n0 = blockIdx.x * 32, c0 = blockIdx.y * 32;
  const int t = threadIdx.x;
  {
    int cc = t >> 3, nn = (t & 7) * 4;
    const float4 v = *(const float4*)&x[((size_t)b * CCH + c0 + cc) * NPIX + n0 + nn];
    tile[cc][nn] = v.x; tile[cc][nn + 1] = v.y; tile[cc][nn + 2] = v.z; tile[cc][nn + 3] = v.w;
  }
  __syncthreads();
  {
    int nr = t >> 3, c4 = (t & 7) * 4;
    ushort4 o;
    o.x = f2b(tile[c4 + 0][nr]); o.y = f2b(tile[c4 + 1][nr]);
    o.z = f2b(tile[c4 + 2][nr]); o.w = f2b(tile[c4 + 3][nr]);
    *(ushort4*)&Xt[((size_t)b * NPIX + n0 + nr) * CCH + c0 + c4] = o;
  }
}

// pack wq(64x512), wk(64x512), wv(512x512) -> Wb[640][512] bf16
__global__ __launch_bounds__(256) void k_cast_w(const float* __restrict__ wq,
                                                const float* __restrict__ wk,
                                                const float* __restrict__ wv,
                                                ushort* __restrict__ Wb) {
  int i = blockIdx.x * 256 + threadIdx.x;
  int idx = i * 4;
  int j = idx >> 9, c = idx & 511;
  const float* src = (j < 64) ? &wq[(size_t)j * 512]
                   : (j < 128) ? &wk[(size_t)(j - 64) * 512]
                               : &wv[(size_t)(j - 128) * 512];
  float4 v = *(const float4*)&src[c];
  ushort4 o; o.x = f2b(v.x); o.y = f2b(v.y); o.z = f2b(v.z); o.w = f2b(v.w);
  *(ushort4*)&Wb[idx] = o;
}

// QKV projection GEMM: out[j,n] = sum_c Wb[j,c]*Xt[n,c] + bias[j]
// Q: [B][N][64] (pre-scaled by LOG2E), K: [B][N][64], V: [B][C][N]  (all bf16)
__global__ __launch_bounds__(256) void k_proj(const ushort* __restrict__ Xt,
                                              const ushort* __restrict__ Wb,
                                              const float* __restrict__ bq,
                                              const float* __restrict__ bk,
                                              const float* __restrict__ bv,
                                              ushort* __restrict__ Q,
                                              ushort* __restrict__ K,
                                              ushort* __restrict__ V) {
  __shared__ ushort Wl[64][72];
  __shared__ ushort Xl[64][72];
  const int b = blockIdx.z;
  const int n0 = blockIdx.x * 64;
  const int j0 = blockIdx.y * 64;
  const int t = threadIdx.x;
  const int w = t >> 6, l = t & 63;
  const int lr = l & 15, lq = l >> 4;
  const int wj = (w >> 1) * 32, wn = (w & 1) * 32;

  f32x4 acc[2][2];
#pragma unroll
  for (int a = 0; a < 2; ++a)
#pragma unroll
    for (int c = 0; c < 2; ++c) acc[a][c] = f32x4{0.f, 0.f, 0.f, 0.f};

  const int srow = t >> 2, sch = t & 3;
  for (int k0 = 0; k0 < 512; k0 += 64) {
    *(uint4*)&Wl[srow][sch * 8]       = *(const uint4*)&Wb[(size_t)(j0 + srow) * 512 + k0 + sch * 8];
    *(uint4*)&Wl[srow][(sch + 4) * 8] = *(const uint4*)&Wb[(size_t)(j0 + srow) * 512 + k0 + (sch + 4) * 8];
    *(uint4*)&Xl[srow][sch * 8]       = *(const uint4*)&Xt[((size_t)b * NPIX + n0 + srow) * 512 + k0 + sch * 8];
    *(uint4*)&Xl[srow][(sch + 4) * 8] = *(const uint4*)&Xt[((size_t)b * NPIX + n0 + srow) * 512 + k0 + (sch + 4) * 8];
    __syncthreads();
#pragma unroll
    for (int kt = 0; kt < 2; ++kt) {
      short8 af[2], bf[2];
#pragma unroll
      for (int jt = 0; jt < 2; ++jt)
        af[jt] = *(const short8*)&Wl[wj + jt * 16 + lr][kt * 32 + lq * 8];
#pragma unroll
      for (int nt = 0; nt < 2; ++nt)
        bf[nt] = *(const short8*)&Xl[wn + nt * 16 + lr][kt * 32 + lq * 8];
#pragma unroll
      for (int jt = 0; jt < 2; ++jt)
#pragma unroll
        for (int nt = 0; nt < 2; ++nt)
          acc[jt][nt] = __builtin_amdgcn_mfma_f32_16x16x32_bf16(af[jt], bf[nt], acc[jt][nt], 0, 0, 0);
    }
    __syncthreads();
  }

#pragma unroll
  for (int jt = 0; jt < 2; ++jt) {
    const int jb = j0 + wj + jt * 16;
#pragma unroll
    for (int nt = 0; nt < 2; ++nt) {
      const int n = n0 + wn + nt * 16 + lr;
      const size_t nrow = (size_t)b * NPIX + n;
      if (jb < 64) {
        // Q pre-scaled by LOG2E so attention uses exp2 directly
        ushort4 o;
        o.x = f2b(LOG2E * (acc[jt][nt][0] + bq[jb + lq * 4 + 0]));
        o.y = f2b(LOG2E * (acc[jt][nt][1] + bq[jb + lq * 4 + 1]));
        o.z = f2b(LOG2E * (acc[jt][nt][2] + bq[jb + lq * 4 + 2]));
        o.w = f2b(LOG2E * (acc[jt][nt][3] + bq[jb + lq * 4 + 3]));
        *(ushort4*)&Q[nrow * DQK + jb + lq * 4] = o;
      } else if (jb < 128) {
        ushort4 o;
        o.x = f2b(acc[jt][nt][0] + bk[jb - 64 + lq * 4 + 0]);
        o.y = f2b(acc[jt][nt][1] + bk[jb - 64 + lq * 4 + 1]);
        o.z = f2b(acc[jt][nt][2] + bk[jb - 64 + lq * 4 + 2]);
        o.w = f2b(acc[jt][nt][3] + bk[jb - 64 + lq * 4 + 3]);
        *(ushort4*)&K[nrow * DQK + jb - 64 + lq * 4] = o;
      } else {
#pragma unroll
        for (int r = 0; r < 4; ++r) {
          int cch = jb - 128 + lq * 4 + r;
          V[((size_t)b * CCH + cch) * NPIX + n] = f2b(acc[jt][nt][r] + bv[cch]);
        }
      }
    }
  }
}

// flash attention v7: 512 thr / 8 waves = 4 q-strips(64q) x 2 c-groups(128c);
// block = 256q x 256c; grid = 16qb x 2cb x 8b = 256 blocks = 1/CU.
// wave = 64q x 128c: each V fragment feeds 2 MFMAs (halves LDS read traffic).
// 3 LDS buffers (120KB), depth-2 prefetch, counted s_waitcnt vmcnt(5).
// P = exp2(S) via native v_exp_f32 (Q pre-scaled by LOG2E; no max, no clamp).
__global__ __launch_bounds__(512, 1) void k_attn(const ushort* __restrict__ Qb,
                                                 const ushort* __restrict__ Kb,
                                                 const ushort* __restrict__ Vb,
                                                 const float* __restrict__ x,
                                                 const float* __restrict__ gamma,
                                                 float* __restrict__ out) {
  __shared__ ushort Sl[3][20480];            // per buf: K 64x64 (4096 us) | V 256x64 (16384 us)
  const int id = blockIdx.x;
  const int b  = id & 7;                     // XCD via %8 round-robin
  const int s_ = id >> 3;                    // 0..31 within XCD
  const int cb = s_ >> 4;                    // 2 c-slices of 256
  const int qb = s_ & 15;                    // 16 q-blocks (consecutive per cb)
  const int t = threadIdx.x;
  const int w = t >> 6, l = t & 63;
  const int lq = l & 31, h = l >> 5;
  const int qw = qb * 256 + (w >> 1) * 64;   // wave's 64-query strip
  const int cloc = (w & 1) * 128;            // wave's local c-base within 256
  const int swz = (lq & 7) << 3;

  // Q fragments (B-operand): lane holds Q[qw+qt*32+lq][ks*16 + h*8 ..]
  short8 qf[2][4];
#pragma unroll
  for (int qt = 0; qt < 2; ++qt)
#pragma unroll
    for (int ks = 0; ks < 4; ++ks)
      qf[qt][ks] = *(const short8*)&Qb[((size_t)b * NPIX + qw + qt * 32 + lq) * DQK + ks * 16 + h * 8];

  f32x16 acc0[4] = {};                       // qt=0: 64q strip rows 0..31
  f32x16 acc1[4] = {};                       // qt=1: rows 32..63
  float L0 = 0.f, L1 = 0.f;

  const size_t kg = (size_t)b * NPIX * DQK;
  const size_t vg = ((size_t)b * CCH + cb * 256) * NPIX;

  auto stage = [&](int buf, int key0) {
    {                                         // K: 512 chunks of 16B, 1/thread
      const int row = t >> 3, cc = t & 7;
      gload16(Kb + kg + (size_t)(key0 + row) * DQK + ((cc ^ (row & 7)) << 3),
              &Sl[buf][w * 512]);
    }
#pragma unroll
    for (int i = 0; i < 4; ++i) {             // V: 2048 chunks of 16B, 4/thread
      const int chunk = i * 512 + t;
      const int row = chunk >> 3, cc = chunk & 7;
      gload16(Vb + vg + (size_t)row * NPIX + key0 + ((cc ^ (row & 7)) << 3),
              &Sl[buf][4096 + i * 4096 + w * 512]);
    }
  };

  stage(0, 0);
  stage(1, 64);
  asm volatile("s_waitcnt vmcnt(5)" ::: "memory");   // buf0 complete
  __builtin_amdgcn_sched_barrier(0);
  __builtin_amdgcn_s_barrier();
  __builtin_amdgcn_sched_barrier(0);

  const int NT = NPIX / 64;
  int buf = 0;
  for (int tt = 0; tt < NT; ++tt) {
    if (tt + 2 < NT) stage((tt + 2) % 3, (tt + 2) * 64);
    const ushort* KL = &Sl[buf][0];
    const ushort* VL = &Sl[buf][4096];

#pragma unroll
    for (int rd = 0; rd < 2; ++rd) {
      short8 kf[4];
#pragma unroll
      for (int ks = 0; ks < 4; ++ks)
        kf[ks] = *(const short8*)&KL[(size_t)(rd * 32 + lq) * 64 + ((ks * 16 + h * 8) ^ swz)];
      short8 vf[4][2];
#pragma unroll
      for (int ct = 0; ct < 4; ++ct)
#pragma unroll
        for (int kt = 0; kt < 2; ++kt)
          vf[ct][kt] = *(const short8*)&VL[(size_t)(cloc + ct * 32 + lq) * 64 +
                                           ((rd * 32 + kt * 16 + h * 8) ^ swz)];

      // S^T = K * Q^T (rows = keys, cols = queries; lane's query = lq)
      f32x16 s0 = {}, s1 = {};
      __builtin_amdgcn_s_setprio(1);
#pragma unroll
      for (int ks = 0; ks < 4; ++ks) {
        s0 = __builtin_amdgcn_mfma_f32_32x32x16_bf16(kf[ks], qf[0][ks], s0, 0, 0, 0);
        s1 = __builtin_amdgcn_mfma_f32_32x32x16_bf16(kf[ks], qf[1][ks], s1, 0, 0, 0);
      }
      __builtin_amdgcn_s_setprio(0);

      auto softpv = [&](f32x16& s, f32x16* accq, float& Lq) {
        float pr[16];
        float sum = 0.f;
#pragma unroll
        for (int r = 0; r < 16; ++r) {
          pr[r] = __builtin_amdgcn_exp2f(s[r]);
          sum += pr[r];
        }
        Lq += sum;
        unsigned pk[8];
#pragma unroll
        for (int j = 0; j < 8; ++j) pk[j] = cvt_pk_bf16(pr[2 * j], pr[2 * j + 1]);
        plane_swap(pk[0], pk[2]); plane_swap(pk[1], pk[3]);
        plane_swap(pk[4], pk[6]); plane_swap(pk[5], pk[7]);
        union { uint4v u; short8 s8; } B0, B1;
        B0.u[0] = pk[0]; B0.u[1] = pk[1]; B0.u[2] = pk[2]; B0.u[3] = pk[3];
        B1.u[0] = pk[4]; B1.u[1] = pk[5]; B1.u[2] = pk[6]; B1.u[3] = pk[7];
        __builtin_amdgcn_s_setprio(1);
#pragma unroll
        for (int ct = 0; ct < 4; ++ct) {
          accq[ct] = __builtin_amdgcn_mfma_f32_32x32x16_bf16(vf[ct][0], B0.s8, accq[ct], 0, 0, 0);
          accq[ct] = __builtin_amdgcn_mfma_f32_32x32x16_bf16(vf[ct][1], B1.s8, accq[ct], 0, 0, 0);
        }
        __builtin_amdgcn_s_setprio(0);
      };
      softpv(s0, acc0, L0);
      softpv(s1, acc1, L1);
    }

    if (tt + 2 < NT) { asm volatile("s_waitcnt vmcnt(5)" ::: "memory"); }
    else             { asm volatile("s_waitcnt vmcnt(0)" ::: "memory"); }
    __builtin_amdgcn_sched_barrier(0);
    __builtin_amdgcn_s_barrier();
    __builtin_amdgcn_sched_barrier(0);
    buf = (buf == 2) ? 0 : buf + 1;
  }

  // epilogue: out[b][c][n] = gamma * O/L + x  (32 contiguous f32 per half-wave)
  L0 += __shfl_xor(L0, 32);
  L1 += __shfl_xor(L1, 32);
  const float g = gamma[0];
  const float gi0 = g / L0, gi1 = g / L1;
#pragma unroll
  for (int ct = 0; ct < 4; ++ct)
#pragma unroll
    for (int r = 0; r < 16; ++r) {
      const int c = cb * 256 + cloc + ct * 32 + (r & 3) + 8 * (r >> 2) + 4 * h;
      const size_t base = ((size_t)b * CCH + c) * NPIX + qw + lq;
      out[base] = gi0 * acc0[ct][r] + x[base];
      out[base + 32] = gi1 * acc1[ct][r] + x[base + 32];
    }
}

extern "C" void kernel_launch(void* const* d_in, const int* in_sizes, int n_in,
                              void* d_out, int out_size, void* d_ws, size_t ws_size,
                              hipStream_t stream) {
  const float* x     = (const float*)d_in[0];
  const float* wq    = (const float*)d_in[1];
  const float* bq    = (const float*)d_in[2];
  const float* wk    = (const float*)d_in[3];
  const float* bk    = (const float*)d_in[4];
  const float* wv    = (const float*)d_in[5];
  const float* bv    = (const float*)d_in[6];
  const float* gamma = (const float*)d_in[7];
  float* out = (float*)d_out;

  // Xt (32MB bf16) lives in d_out (64MB) — dead before k_attn writes the output.
  ushort* Xt = (ushort*)d_out;
  ushort* Wb = (ushort*)d_ws;                          // 640*512
  ushort* Qb = Wb + (size_t)640 * 512;                 // 8*4096*64
  ushort* Kb = Qb + (size_t)8 * NPIX * DQK;            // 8*4096*64
  ushort* Vb = Kb + (size_t)8 * NPIX * DQK;            // 8*512*4096
  // total ws: ~42.6 MB

  k_cast_x<<<dim3(NPIX / 32, CCH / 32, 8), 256, 0, stream>>>(x, Xt);
  k_cast_w<<<(640 * 512 / 4) / 256, 256, 0, stream>>>(wq, wk, wv, Wb);
  k_proj<<<dim3(NPIX / 64, 640 / 64, 8), 256, 0, stream>>>(Xt, Wb, bq, bk, bv, Qb, Kb, Vb);
  k_attn<<<dim3(256), 512, 0, stream>>>(Qb, Kb, Vb, x, gamma, out);
}

// Round 8
// 317.497 us; speedup vs baseline: 4.5646x; 4.5646x over previous
//
#include <hip/hip_runtime.h>

typedef float  f32x4  __attribute__((ext_vector_type(4)));
typedef float  f32x16 __attribute__((ext_vector_type(16)));
typedef short  short8 __attribute__((ext_vector_type(8)));
typedef unsigned int uint4v __attribute__((ext_vector_type(4)));

#define LOG2E 1.4426950408889634f
#define NPIX 4096
#define CCH  512
#define DQK  64

__device__ __forceinline__ ushort f2b(float f) {
  union { float f; unsigned u; } v; v.f = f;
  unsigned r = v.u + 0x7fffu + ((v.u >> 16) & 1u);
  return (ushort)(r >> 16);
}

__device__ __forceinline__ unsigned cvt_pk_bf16(float lo, float hi) {
  unsigned r;
  asm("v_cvt_pk_bf16_f32 %0, %1, %2" : "=v"(r) : "v"(lo), "v"(hi));
  return r;
}

// in-place half-swap: a' = {a[0:32), b[0:32)}, b' = {a[32:64), b[32:64)}
__device__ __forceinline__ void plane_swap(unsigned &a, unsigned &b) {
  asm volatile("v_permlane32_swap_b32 %0, %1" : "+v"(a), "+v"(b));
}

// async 16B global -> LDS (dest = wave-uniform base + lane*16)
__device__ __forceinline__ void gload16(const ushort* g, ushort* l) {
  __builtin_amdgcn_global_load_lds((const __attribute__((address_space(1))) void*)g,
                                   (__attribute__((address_space(3))) void*)l, 16, 0, 0);
}

// x: [B][C][N] f32  ->  Xt: [B][N][C] bf16  (tiled transpose via LDS)
__global__ __launch_bounds__(256) void k_cast_x(const float* __restrict__ x,
                                                ushort* __restrict__ Xt) {
  __shared__ float tile[32][33];
  const int b = blockIdx.z;
  const int n0 = blockIdx.x * 32, c0 = blockIdx.y * 32;
  const int t = threadIdx.x;
  {
    int cc = t >> 3, nn = (t & 7) * 4;
    const float4 v = *(const float4*)&x[((size_t)b * CCH + c0 + cc) * NPIX + n0 + nn];
    tile[cc][nn] = v.x; tile[cc][nn + 1] = v.y; tile[cc][nn + 2] = v.z; tile[cc][nn + 3] = v.w;
  }
  __syncthreads();
  {
    int nr = t >> 3, c4 = (t & 7) * 4;
    ushort4 o;
    o.x = f2b(tile[c4 + 0][nr]); o.y = f2b(tile[c4 + 1][nr]);
    o.z = f2b(tile[c4 + 2][nr]); o.w = f2b(tile[c4 + 3][nr]);
    *(ushort4*)&Xt[((size_t)b * NPIX + n0 + nr) * CCH + c0 + c4] = o;
  }
}

// pack wq(64x512), wk(64x512), wv(512x512) -> Wb[640][512] bf16
__global__ __launch_bounds__(256) void k_cast_w(const float* __restrict__ wq,
                                                const float* __restrict__ wk,
                                                const float* __restrict__ wv,
                                                ushort* __restrict__ Wb) {
  int i = blockIdx.x * 256 + threadIdx.x;
  int idx = i * 4;
  int j = idx >> 9, c = idx & 511;
  const float* src = (j < 64) ? &wq[(size_t)j * 512]
                   : (j < 128) ? &wk[(size_t)(j - 64) * 512]
                               : &wv[(size_t)(j - 128) * 512];
  float4 v = *(const float4*)&src[c];
  ushort4 o; o.x = f2b(v.x); o.y = f2b(v.y); o.z = f2b(v.z); o.w = f2b(v.w);
  *(ushort4*)&Wb[idx] = o;
}

// QKV projection GEMM: out[j,n] = sum_c Wb[j,c]*Xt[n,c] + bias[j]
// Q: [B][N][64] (pre-scaled by LOG2E), K: [B][N][64], V: [B][C][N]  (all bf16)
__global__ __launch_bounds__(256) void k_proj(const ushort* __restrict__ Xt,
                                              const ushort* __restrict__ Wb,
                                              const float* __restrict__ bq,
                                              const float* __restrict__ bk,
                                              const float* __restrict__ bv,
                                              ushort* __restrict__ Q,
                                              ushort* __restrict__ K,
                                              ushort* __restrict__ V) {
  __shared__ ushort Wl[64][72];
  __shared__ ushort Xl[64][72];
  const int b = blockIdx.z;
  const int n0 = blockIdx.x * 64;
  const int j0 = blockIdx.y * 64;
  const int t = threadIdx.x;
  const int w = t >> 6, l = t & 63;
  const int lr = l & 15, lq = l >> 4;
  const int wj = (w >> 1) * 32, wn = (w & 1) * 32;

  f32x4 acc[2][2];
#pragma unroll
  for (int a = 0; a < 2; ++a)
#pragma unroll
    for (int c = 0; c < 2; ++c) acc[a][c] = f32x4{0.f, 0.f, 0.f, 0.f};

  const int srow = t >> 2, sch = t & 3;
  for (int k0 = 0; k0 < 512; k0 += 64) {
    *(uint4*)&Wl[srow][sch * 8]       = *(const uint4*)&Wb[(size_t)(j0 + srow) * 512 + k0 + sch * 8];
    *(uint4*)&Wl[srow][(sch + 4) * 8] = *(const uint4*)&Wb[(size_t)(j0 + srow) * 512 + k0 + (sch + 4) * 8];
    *(uint4*)&Xl[srow][sch * 8]       = *(const uint4*)&Xt[((size_t)b * NPIX + n0 + srow) * 512 + k0 + sch * 8];
    *(uint4*)&Xl[srow][(sch + 4) * 8] = *(const uint4*)&Xt[((size_t)b * NPIX + n0 + srow) * 512 + k0 + (sch + 4) * 8];
    __syncthreads();
#pragma unroll
    for (int kt = 0; kt < 2; ++kt) {
      short8 af[2], bf[2];
#pragma unroll
      for (int jt = 0; jt < 2; ++jt)
        af[jt] = *(const short8*)&Wl[wj + jt * 16 + lr][kt * 32 + lq * 8];
#pragma unroll
      for (int nt = 0; nt < 2; ++nt)
        bf[nt] = *(const short8*)&Xl[wn + nt * 16 + lr][kt * 32 + lq * 8];
#pragma unroll
      for (int jt = 0; jt < 2; ++jt)
#pragma unroll
        for (int nt = 0; nt < 2; ++nt)
          acc[jt][nt] = __builtin_amdgcn_mfma_f32_16x16x32_bf16(af[jt], bf[nt], acc[jt][nt], 0, 0, 0);
    }
    __syncthreads();
  }

#pragma unroll
  for (int jt = 0; jt < 2; ++jt) {
    const int jb = j0 + wj + jt * 16;
#pragma unroll
    for (int nt = 0; nt < 2; ++nt) {
      const int n = n0 + wn + nt * 16 + lr;
      const size_t nrow = (size_t)b * NPIX + n;
      if (jb < 64) {
        // Q pre-scaled by LOG2E so attention uses exp2 directly
        ushort4 o;
        o.x = f2b(LOG2E * (acc[jt][nt][0] + bq[jb + lq * 4 + 0]));
        o.y = f2b(LOG2E * (acc[jt][nt][1] + bq[jb + lq * 4 + 1]));
        o.z = f2b(LOG2E * (acc[jt][nt][2] + bq[jb + lq * 4 + 2]));
        o.w = f2b(LOG2E * (acc[jt][nt][3] + bq[jb + lq * 4 + 3]));
        *(ushort4*)&Q[nrow * DQK + jb + lq * 4] = o;
      } else if (jb < 128) {
        ushort4 o;
        o.x = f2b(acc[jt][nt][0] + bk[jb - 64 + lq * 4 + 0]);
        o.y = f2b(acc[jt][nt][1] + bk[jb - 64 + lq * 4 + 1]);
        o.z = f2b(acc[jt][nt][2] + bk[jb - 64 + lq * 4 + 2]);
        o.w = f2b(acc[jt][nt][3] + bk[jb - 64 + lq * 4 + 3]);
        *(ushort4*)&K[nrow * DQK + jb - 64 + lq * 4] = o;
      } else {
#pragma unroll
        for (int r = 0; r < 4; ++r) {
          int cch = jb - 128 + lq * 4 + r;
          V[((size_t)b * CCH + cch) * NPIX + n] = f2b(acc[jt][nt][r] + bv[cch]);
        }
      }
    }
  }
}

// flash attention v8: 512 thr / 8 waves = 4 q-strips(64q) x 2 c-groups(128c);
// block = 256q x 256c; grid = 16qb x 2cb x 8b = 256 blocks = 1/CU.
// wave = 64q x 128c: each V fragment feeds 2 MFMAs. All softmax/PV state in
// NAMED registers (no pointer indirection -> no scratch; R7 lesson).
// 3 LDS buffers (120KB), depth-2 prefetch, counted s_waitcnt vmcnt(5).
// P = exp2(S) (Q pre-scaled by LOG2E; no max, no clamp).
__global__ __launch_bounds__(512, 1) void k_attn(const ushort* __restrict__ Qb,
                                                 const ushort* __restrict__ Kb,
                                                 const ushort* __restrict__ Vb,
                                                 const float* __restrict__ x,
                                                 const float* __restrict__ gamma,
                                                 float* __restrict__ out) {
  __shared__ ushort Sl[3][20480];            // per buf: K 64x64 (4096 us) | V 256x64 (16384 us)
  const int id = blockIdx.x;
  const int b  = id & 7;                     // XCD via %8 round-robin
  const int s_ = id >> 3;                    // 0..31 within XCD
  const int cb = s_ >> 4;                    // 2 c-slices of 256
  const int qb = s_ & 15;                    // 16 q-blocks (consecutive per cb)
  const int t = threadIdx.x;
  const int w = t >> 6, l = t & 63;
  const int lq = l & 31, h = l >> 5;
  const int qw = qb * 256 + (w >> 1) * 64;   // wave's 64-query strip
  const int cloc = (w & 1) * 128;            // wave's local c-base within 256
  const int swz = (lq & 7) << 3;

  // Q fragments (B-operand): lane holds Q[qw+qt*32+lq][ks*16 + h*8 ..]
  short8 qf0[4], qf1[4];
#pragma unroll
  for (int ks = 0; ks < 4; ++ks) {
    qf0[ks] = *(const short8*)&Qb[((size_t)b * NPIX + qw + lq) * DQK + ks * 16 + h * 8];
    qf1[ks] = *(const short8*)&Qb[((size_t)b * NPIX + qw + 32 + lq) * DQK + ks * 16 + h * 8];
  }

  f32x16 acc0[4] = {};                       // q rows 0..31 of strip
  f32x16 acc1[4] = {};                       // q rows 32..63
  float L0 = 0.f, L1 = 0.f;

  const size_t kg = (size_t)b * NPIX * DQK;
  const size_t vg = ((size_t)b * CCH + cb * 256) * NPIX;

  auto stage = [&](int buf, int key0) {
    {                                         // K: 512 chunks of 16B, 1/thread
      const int row = t >> 3, cc = t & 7;
      gload16(Kb + kg + (size_t)(key0 + row) * DQK + ((cc ^ (row & 7)) << 3),
              &Sl[buf][w * 512]);
    }
#pragma unroll
    for (int i = 0; i < 4; ++i) {             // V: 2048 chunks of 16B, 4/thread
      const int chunk = i * 512 + t;
      const int row = chunk >> 3, cc = chunk & 7;
      gload16(Vb + vg + (size_t)row * NPIX + key0 + ((cc ^ (row & 7)) << 3),
              &Sl[buf][4096 + i * 4096 + w * 512]);
    }
  };

  stage(0, 0);
  stage(1, 64);
  asm volatile("s_waitcnt vmcnt(5)" ::: "memory");   // buf0 complete
  __builtin_amdgcn_sched_barrier(0);
  __builtin_amdgcn_s_barrier();
  __builtin_amdgcn_sched_barrier(0);

  const int NT = NPIX / 64;
  int buf = 0;
  for (int tt = 0; tt < NT; ++tt) {
    if (tt + 2 < NT) stage((tt + 2) % 3, (tt + 2) * 64);
    const ushort* KL = &Sl[buf][0];
    const ushort* VL = &Sl[buf][4096];

#pragma unroll
    for (int rd = 0; rd < 2; ++rd) {
      short8 kf[4];
#pragma unroll
      for (int ks = 0; ks < 4; ++ks)
        kf[ks] = *(const short8*)&KL[(size_t)(rd * 32 + lq) * 64 + ((ks * 16 + h * 8) ^ swz)];

      // S^T = K * Q^T (rows = keys, cols = queries; lane's query = lq)
      f32x16 s0 = {}, s1 = {};
      __builtin_amdgcn_s_setprio(1);
#pragma unroll
      for (int ks = 0; ks < 4; ++ks) {
        s0 = __builtin_amdgcn_mfma_f32_32x32x16_bf16(kf[ks], qf0[ks], s0, 0, 0, 0);
        s1 = __builtin_amdgcn_mfma_f32_32x32x16_bf16(kf[ks], qf1[ks], s1, 0, 0, 0);
      }
      __builtin_amdgcn_s_setprio(0);

      // softmax qt0: P = exp2(S') in-place, rowsum, pack to bf16 B-fragments
      float sum0 = 0.f;
#pragma unroll
      for (int r = 0; r < 16; ++r) { s0[r] = __builtin_amdgcn_exp2f(s0[r]); sum0 += s0[r]; }
      L0 += sum0;
      unsigned pk0[8];
#pragma unroll
      for (int j = 0; j < 8; ++j) pk0[j] = cvt_pk_bf16(s0[2 * j], s0[2 * j + 1]);
      plane_swap(pk0[0], pk0[2]); plane_swap(pk0[1], pk0[3]);
      plane_swap(pk0[4], pk0[6]); plane_swap(pk0[5], pk0[7]);
      union { uint4v u; short8 s8; } B00, B10;
      B00.u[0] = pk0[0]; B00.u[1] = pk0[1]; B00.u[2] = pk0[2]; B00.u[3] = pk0[3];
      B10.u[0] = pk0[4]; B10.u[1] = pk0[5]; B10.u[2] = pk0[6]; B10.u[3] = pk0[7];

      // softmax qt1
      float sum1 = 0.f;
#pragma unroll
      for (int r = 0; r < 16; ++r) { s1[r] = __builtin_amdgcn_exp2f(s1[r]); sum1 += s1[r]; }
      L1 += sum1;
      unsigned pk1[8];
#pragma unroll
      for (int j = 0; j < 8; ++j) pk1[j] = cvt_pk_bf16(s1[2 * j], s1[2 * j + 1]);
      plane_swap(pk1[0], pk1[2]); plane_swap(pk1[1], pk1[3]);
      plane_swap(pk1[4], pk1[6]); plane_swap(pk1[5], pk1[7]);
      union { uint4v u; short8 s8; } B01, B11;
      B01.u[0] = pk1[0]; B01.u[1] = pk1[1]; B01.u[2] = pk1[2]; B01.u[3] = pk1[3];
      B11.u[0] = pk1[4]; B11.u[1] = pk1[5]; B11.u[2] = pk1[6]; B11.u[3] = pk1[7];

      // PV: each V fragment pair feeds both q-tiles (2x MFMA per LDS byte)
      __builtin_amdgcn_s_setprio(1);
#pragma unroll
      for (int ct = 0; ct < 4; ++ct) {
        const size_t vrow = (size_t)(cloc + ct * 32 + lq) * 64;
        short8 v0 = *(const short8*)&VL[vrow + ((rd * 32 + 0 + h * 8) ^ swz)];
        short8 v1 = *(const short8*)&VL[vrow + ((rd * 32 + 16 + h * 8) ^ swz)];
        acc0[ct] = __builtin_amdgcn_mfma_f32_32x32x16_bf16(v0, B00.s8, acc0[ct], 0, 0, 0);
        acc0[ct] = __builtin_amdgcn_mfma_f32_32x32x16_bf16(v1, B10.s8, acc0[ct], 0, 0, 0);
        acc1[ct] = __builtin_amdgcn_mfma_f32_32x32x16_bf16(v0, B01.s8, acc1[ct], 0, 0, 0);
        acc1[ct] = __builtin_amdgcn_mfma_f32_32x32x16_bf16(v1, B11.s8, acc1[ct], 0, 0, 0);
      }
      __builtin_amdgcn_s_setprio(0);
    }

    if (tt + 2 < NT) { asm volatile("s_waitcnt vmcnt(5)" ::: "memory"); }
    else             { asm volatile("s_waitcnt vmcnt(0)" ::: "memory"); }
    __builtin_amdgcn_sched_barrier(0);
    __builtin_amdgcn_s_barrier();
    __builtin_amdgcn_sched_barrier(0);
    buf = (buf == 2) ? 0 : buf + 1;
  }

  // epilogue: out[b][c][n] = gamma * O/L + x  (32 contiguous f32 per half-wave)
  L0 += __shfl_xor(L0, 32);
  L1 += __shfl_xor(L1, 32);
  const float g = gamma[0];
  const float gi0 = g / L0, gi1 = g / L1;
#pragma unroll
  for (int ct = 0; ct < 4; ++ct)
#pragma unroll
    for (int r = 0; r < 16; ++r) {
      const int c = cb * 256 + cloc + ct * 32 + (r & 3) + 8 * (r >> 2) + 4 * h;
      const size_t base = ((size_t)b * CCH + c) * NPIX + qw + lq;
      out[base] = gi0 * acc0[ct][r] + x[base];
      out[base + 32] = gi1 * acc1[ct][r] + x[base + 32];
    }
}

extern "C" void kernel_launch(void* const* d_in, const int* in_sizes, int n_in,
                              void* d_out, int out_size, void* d_ws, size_t ws_size,
                              hipStream_t stream) {
  const float* x     = (const float*)d_in[0];
  const float* wq    = (const float*)d_in[1];
  const float* bq    = (const float*)d_in[2];
  const float* wk    = (const float*)d_in[3];
  const float* bk    = (const float*)d_in[4];
  const float* wv    = (const float*)d_in[5];
  const float* bv    = (const float*)d_in[6];
  const float* gamma = (const float*)d_in[7];
  float* out = (float*)d_out;

  // Xt (32MB bf16) lives in d_out (64MB) — dead before k_attn writes the output.
  ushort* Xt = (ushort*)d_out;
  ushort* Wb = (ushort*)d_ws;                          // 640*512
  ushort* Qb = Wb + (size_t)640 * 512;                 // 8*4096*64
  ushort* Kb = Qb + (size_t)8 * NPIX * DQK;            // 8*4096*64
  ushort* Vb = Kb + (size_t)8 * NPIX * DQK;            // 8*512*4096
  // total ws: ~42.6 MB

  k_cast_x<<<dim3(NPIX / 32, CCH / 32, 8), 256, 0, stream>>>(x, Xt);
  k_cast_w<<<(640 * 512 / 4) / 256, 256, 0, stream>>>(wq, wk, wv, Wb);
  k_proj<<<dim3(NPIX / 64, 640 / 64, 8), 256, 0, stream>>>(Xt, Wb, bq, bk, bv, Qb, Kb, Vb);
  k_attn<<<dim3(256), 512, 0, stream>>>(Qb, Kb, Vb, x, gamma, out);
}